// Round 8
// baseline (206.161 us; speedup 1.0000x reference)
//
#include <hip/hip_runtime.h>
#include <cmath>

// Bokeh render, gather form:
// out[b,c,y,x] = sum_{dy,dx in [-4,4]} w * img[b,c,y-dy,x-dx] / sum w
// w = sigmoid(8*(r_src - dist)) / max(pi*r_src^2,1);  r = |defocus| in [0,4).
// Window mask dropped (outside-window w <= sigma(-8): output shift <2e-5).
// OOB sources exact via Iv=0.
//
// R8: LDS-instruction minimization. R4-R7 established: per-CU LDS pipe with
// ~20cyc/b128 conflict overhead (unmodelable, 3 failed theories) dominates.
// Fix: each lane ds_reads ONLY its own aligned quad (3 b128/row, was 9);
// neighbor quads come via v_mov_b32_dpp row_shl:1/2 (VALU pipe, per-SIMD).
// Every surviving LDS read = 16 lanes x 64 contiguous dwords (m134-proven
// conflict-free). Costs: TW=56 (padded row = exactly 16 quads), lanes 14/15
// compute-masked, ragged grid-x. fd table now a by-value kernarg (s_load,
// compile-time index) -- wr loop fully unrolled with per-row memory fences
// to cap the live set (R1 spill lesson).

#define HH 512
#define WW 512
#define NB 2
#define TW 56                     // output tile width (14 quads)
#define TH 16                     // output tile height
#define HALO 4
#define SROWS (TH + 2 * HALO)     // 24
#define PCOLS 64                  // padded row: 16 quads exactly
#define LW 68                     // row stride in dwords (16B-aligned rows)

struct FdTab { float fd[9][9]; };  // exp(8*dist(dy,dx))

__device__ __forceinline__ unsigned rtne_hi(float v) {
  unsigned u = __float_as_uint(v);
  u = u + 0x7FFFu + ((u >> 16) & 1u);
  return u & 0xFFFF0000u;
}
// lane i <- lane i+N within each 16-lane DPP row; shifted-in lanes get 0.
__device__ __forceinline__ unsigned dpp_shl1(unsigned v) {
  return (unsigned)__builtin_amdgcn_update_dpp(0, (int)v, 0x101, 0xF, 0xF, true);
}
__device__ __forceinline__ unsigned dpp_shl2(unsigned v) {
  return (unsigned)__builtin_amdgcn_update_dpp(0, (int)v, 0x102, 0xF, 0xF, true);
}

__global__ __launch_bounds__(256, 4) void bokeh_gather(
    const float* __restrict__ img,
    const float* __restrict__ def,
    float* __restrict__ out,
    FdTab cst)
{
  __shared__ __align__(16) unsigned sX[SROWS][LW];  // G(hi) | Iv(lo)   bf16
  __shared__ __align__(16) unsigned sY[SROWS][LW];  // c0(hi) | c1(lo)  bf16
  __shared__ __align__(16) unsigned sZ[SROWS][LW];  // c2 truncated f32

  const int tid = threadIdx.x;
  const int tx  = tid & 15;      // 16 lanes per DPP row
  const int ty  = tid >> 4;      // 16 output rows
  const int bx = blockIdx.x * TW;
  const int by = blockIdx.y * TH;
  const int b  = blockIdx.z;

  const float* dpt = def + b * (HH * WW);
  const float* ipt = img + b * (3 * HH * WW);

  // Stage halo'd tile: padded col lx in [0,64) <-> tile col lx-4.
  // 24*64/256 = 6 iters; lanes 0..63 cover one full row -> coalesced global,
  // contiguous LDS writes. OOB -> zeros => w = 0 exactly.
  #pragma unroll
  for (int it = 0; it < 6; ++it) {
    int idx = tid + it * 256;
    int ly = idx >> 6;
    int lx = idx & 63;
    int sy = by - HALO + ly;
    int sx = bx - HALO + lx;
    unsigned X = 0u, Y = 0u, Z = 0u;
    if ((unsigned)sy < (unsigned)HH && (unsigned)sx < (unsigned)WW) {
      int o = sy * WW + sx;
      float r = fabsf(dpt[o]);
      float G  = __expf(-8.0f * r);
      float iv = __builtin_amdgcn_rcpf(fmaxf(3.14159265358979f * r * r, 1.0f));
      X = rtne_hi(G) | (rtne_hi(iv) >> 16);
      Y = rtne_hi(ipt[o]) | (rtne_hi(ipt[o + HH * WW]) >> 16);
      Z = __float_as_uint(ipt[o + 2 * HH * WW]) & 0xFFFF0000u;
    }
    sX[ly][lx] = X;
    sY[ly][lx] = Y;
    sZ[ly][lx] = Z;
  }
  __syncthreads();

  float wsum[4] = {0.f, 0.f, 0.f, 0.f};
  float ac0[4]  = {0.f, 0.f, 0.f, 0.f};
  float ac1[4]  = {0.f, 0.f, 0.f, 0.f};
  float ac2[4]  = {0.f, 0.f, 0.f, 0.f};

  const int qcol = 4 * tx;       // own quad, 16B aligned

  #pragma unroll
  for (int wr = 0; wr < 9; ++wr) {
    const int sr = ty + wr;
    // Own quad only: per 16-lane row this is 64 contiguous dwords.
    uint4 X = *(const uint4*)&sX[sr][qcol];
    uint4 Y = *(const uint4*)&sY[sr][qcol];
    uint4 Z = *(const uint4*)&sZ[sr][qcol];

    // 12-px window buffer: own quad + right-neighbor quads via DPP.
    unsigned Xv[12], Yv[12], Zv[12];
    Xv[0]=X.x; Xv[1]=X.y; Xv[2]=X.z; Xv[3]=X.w;
    Yv[0]=Y.x; Yv[1]=Y.y; Yv[2]=Y.z; Yv[3]=Y.w;
    Zv[0]=Z.x; Zv[1]=Z.y; Zv[2]=Z.z; Zv[3]=Z.w;
    Xv[4]=dpp_shl1(X.x); Xv[5]=dpp_shl1(X.y); Xv[6]=dpp_shl1(X.z); Xv[7]=dpp_shl1(X.w);
    Yv[4]=dpp_shl1(Y.x); Yv[5]=dpp_shl1(Y.y); Yv[6]=dpp_shl1(Y.z); Yv[7]=dpp_shl1(Y.w);
    Zv[4]=dpp_shl1(Z.x); Zv[5]=dpp_shl1(Z.y); Zv[6]=dpp_shl1(Z.z); Zv[7]=dpp_shl1(Z.w);
    Xv[8]=dpp_shl2(X.x); Xv[9]=dpp_shl2(X.y); Xv[10]=dpp_shl2(X.z); Xv[11]=dpp_shl2(X.w);
    Yv[8]=dpp_shl2(Y.x); Yv[9]=dpp_shl2(Y.y); Yv[10]=dpp_shl2(Y.z); Yv[11]=dpp_shl2(Y.w);
    Zv[8]=dpp_shl2(Z.x); Zv[9]=dpp_shl2(Z.y); Zv[10]=dpp_shl2(Z.z); Zv[11]=dpp_shl2(Z.w);

    float Gv[12], Iv[12], C0[12], C1[12];
    #pragma unroll
    for (int j = 0; j < 12; ++j) {
      Gv[j] = __uint_as_float(Xv[j] & 0xFFFF0000u);
      Iv[j] = __uint_as_float(Xv[j] << 16);
      C0[j] = __uint_as_float(Yv[j] & 0xFFFF0000u);
      C1[j] = __uint_as_float(Yv[j] << 16);
    }

    #pragma unroll
    for (int k = 0; k < 4; ++k) {
      #pragma unroll
      for (int j = k; j < k + 9; ++j) {
        const int xi = j - k;                       // compile-time
        float tden = fmaf(Gv[j], cst.fd[wr][xi], 1.0f);  // 1 + e^{-8r}e^{8d}
        float w = __builtin_amdgcn_rcpf(tden) * Iv[j];
        wsum[k] += w;
        ac0[k] = fmaf(w, C0[j], ac0[k]);
        ac1[k] = fmaf(w, C1[j], ac1[k]);
        ac2[k] = fmaf(w, __uint_as_float(Zv[j]), ac2[k]);
      }
    }
    // Keep live set ~1 row: next row's LDS reads can't hoist above here.
    asm volatile("" ::: "memory");
  }

  const int ox = bx + 4 * tx;
  if (4 * tx < TW && ox < WW) {
    const int oy = by + ty;
    float rw[4];
    #pragma unroll
    for (int k = 0; k < 4; ++k) rw[k] = __builtin_amdgcn_rcpf(wsum[k]);
    float* op0 = out + ((b * 3 + 0) * HH + oy) * WW + ox;
    float* op1 = out + ((b * 3 + 1) * HH + oy) * WW + ox;
    float* op2 = out + ((b * 3 + 2) * HH + oy) * WW + ox;
    float4 v0, v1, v2;
    v0.x = ac0[0] * rw[0]; v0.y = ac0[1] * rw[1]; v0.z = ac0[2] * rw[2]; v0.w = ac0[3] * rw[3];
    v1.x = ac1[0] * rw[0]; v1.y = ac1[1] * rw[1]; v1.z = ac1[2] * rw[2]; v1.w = ac1[3] * rw[3];
    v2.x = ac2[0] * rw[0]; v2.y = ac2[1] * rw[1]; v2.z = ac2[2] * rw[2]; v2.w = ac2[3] * rw[3];
    *(float4*)op0 = v0;
    *(float4*)op1 = v1;
    *(float4*)op2 = v2;
  }
}

extern "C" void kernel_launch(void* const* d_in, const int* in_sizes, int n_in,
                              void* d_out, int out_size, void* d_ws, size_t ws_size,
                              hipStream_t stream) {
  const float* img = (const float*)d_in[0];   // (2,3,512,512) f32
  const float* def = (const float*)d_in[1];   // (2,1,512,512) f32
  float* out = (float*)d_out;                 // (2,3,512,512) f32

  FdTab cst;
  for (int dy = 0; dy < 9; ++dy)
    for (int dx = 0; dx < 9; ++dx) {
      float dyo = (float)(dy - 4), dxo = (float)(dx - 4);
      cst.fd[dy][dx] = expf(8.0f * sqrtf(dyo * dyo + dxo * dxo));
    }

  dim3 grid((WW + TW - 1) / TW, HH / TH, NB);  // 10 x 32 x 2 = 640 blocks
  dim3 block(256);
  hipLaunchKernelGGL(bokeh_gather, grid, block, 0, stream, img, def, out, cst);
}

// Round 9
// 24.041 us; speedup vs baseline: 8.5753x; 8.5753x over previous
//
#include <hip/hip_runtime.h>
#include <cmath>

// Bokeh render, gather form:
// out[b,c,y,x] = sum_{dy,dx in [-4,4]} w * img[b,c,y-dy,x-dx] / sum w
// w = sigmoid(8*(r_src - dist)) / max(pi*r_src^2,1);  r = |defocus| in [0,4).
// Window mask dropped (outside-window w <= sigma(-8): output shift <2e-5).
// OOB sources exact via Iv=0.
//
// R9 = R7's proven-clean loop structure + R8's own-quad/DPP idea:
//  - Each lane ds_reads ONLY its own aligned quad per array (3 b128/row,
//    was 9); neighbor quads via v_mov_b32_dpp row_shl:1/2 (VALU pipe).
//    DPP direction lane i <- lane i+N was correctness-verified in R8.
//  - R8's 206us regression was SCRATCH (370MB writes/dispatch): the asm
//    "memory" fences inside the unrolled loop blocked array promotion.
//    Fix: no fences, "#pragma unroll 1" row loop (R7-proven no-scratch),
//    per-row fd from the sFd LDS broadcast table (R7-proven).
//  - Geometry: TW=56 (padded row = exactly 16 quads), TH=16, 256 thr,
//    grid 10x32x2 = 640 blocks (2.5 blk/CU). Lanes tx>=14 compute-idle.

#define HH 512
#define WW 512
#define NB 2
#define TW 56                     // output tile width (14 quads)
#define TH 16                     // output tile height
#define HALO 4
#define SROWS (TH + 2 * HALO)     // 24
#define LW 68                     // row stride in dwords (16B-aligned rows)

__device__ __forceinline__ unsigned rtne_hi(float v) {
  // bf16 round-to-nearest-even, result in HIGH 16 bits (low 16 zero).
  unsigned u = __float_as_uint(v);
  u = u + 0x7FFFu + ((u >> 16) & 1u);
  return u & 0xFFFF0000u;
}
// lane i <- lane i+N within each 16-lane DPP row (verified R8); edge -> 0.
__device__ __forceinline__ unsigned dpp_shl1(unsigned v) {
  return (unsigned)__builtin_amdgcn_update_dpp(0, (int)v, 0x101, 0xF, 0xF, true);
}
__device__ __forceinline__ unsigned dpp_shl2(unsigned v) {
  return (unsigned)__builtin_amdgcn_update_dpp(0, (int)v, 0x102, 0xF, 0xF, true);
}

__global__ __launch_bounds__(256, 4) void bokeh_gather(
    const float* __restrict__ img,
    const float* __restrict__ def,
    float* __restrict__ out)
{
  __shared__ __align__(16) unsigned sX[SROWS][LW];  // G(hi) | Iv(lo)   bf16
  __shared__ __align__(16) unsigned sY[SROWS][LW];  // c0(hi) | c1(lo)  bf16
  __shared__ __align__(16) unsigned sZ[SROWS][LW];  // c2 truncated f32
  __shared__ float sFd[9][12];                      // exp(8*dist(dy,dx))

  const int tid = threadIdx.x;
  const int tx  = tid & 15;      // 16 lanes per DPP row; lane owns quad tx
  const int ty  = tid >> 4;      // 16 output rows
  const int bx = blockIdx.x * TW;
  const int by = blockIdx.y * TH;
  const int b  = blockIdx.z;

  if (tid < 81) {
    int dyi = tid / 9, dxi = tid - dyi * 9;
    int dyo = dyi - 4, dxo = dxi - 4;
    float d2 = (float)(dyo * dyo + dxo * dxo);
    sFd[dyi][dxi] = __expf(8.0f * sqrtf(d2));
  }

  const float* dpt = def + b * (HH * WW);
  const float* ipt = img + b * (3 * HH * WW);

  // Stage halo'd tile: padded col lx in [0,64) <-> tile col lx-4.
  // 24 rows x 64 cols / 256 thr = 6 iters, coalesced. OOB -> zeros => w=0.
  #pragma unroll
  for (int it = 0; it < 6; ++it) {
    int idx = tid + it * 256;
    int ly = idx >> 6;
    int lx = idx & 63;
    int sy = by - HALO + ly;
    int sx = bx - HALO + lx;
    unsigned X = 0u, Y = 0u, Z = 0u;
    if ((unsigned)sy < (unsigned)HH && (unsigned)sx < (unsigned)WW) {
      int o = sy * WW + sx;
      float r = fabsf(dpt[o]);
      float G  = __expf(-8.0f * r);
      float iv = __builtin_amdgcn_rcpf(fmaxf(3.14159265358979f * r * r, 1.0f));
      X = rtne_hi(G) | (rtne_hi(iv) >> 16);
      Y = rtne_hi(ipt[o]) | (rtne_hi(ipt[o + HH * WW]) >> 16);
      Z = __float_as_uint(ipt[o + 2 * HH * WW]) & 0xFFFF0000u;
    }
    sX[ly][lx] = X;
    sY[ly][lx] = Y;
    sZ[ly][lx] = Z;
  }
  __syncthreads();

  float wsum[4] = {0.f, 0.f, 0.f, 0.f};
  float ac0[4]  = {0.f, 0.f, 0.f, 0.f};
  float ac1[4]  = {0.f, 0.f, 0.f, 0.f};
  float ac2[4]  = {0.f, 0.f, 0.f, 0.f};

  const int qcol = 4 * tx;       // own quad, 16B aligned

  #pragma unroll 1
  for (int wr = 0; wr < 9; ++wr) {
    const int sr = ty + wr;
    float fdr[9];
    #pragma unroll
    for (int x = 0; x < 9; ++x) fdr[x] = sFd[wr][x];

    // Own quad only: each 16-lane group reads 64 contiguous dwords.
    uint4 X = *(const uint4*)&sX[sr][qcol];
    uint4 Y = *(const uint4*)&sY[sr][qcol];
    uint4 Z = *(const uint4*)&sZ[sr][qcol];

    // 12-px window: own quad + right neighbors via DPP (lane i <- i+N).
    unsigned Xv[12], Yv[12], Zv[12];
    Xv[0]=X.x; Xv[1]=X.y; Xv[2]=X.z; Xv[3]=X.w;
    Yv[0]=Y.x; Yv[1]=Y.y; Yv[2]=Y.z; Yv[3]=Y.w;
    Zv[0]=Z.x; Zv[1]=Z.y; Zv[2]=Z.z; Zv[3]=Z.w;
    Xv[4]=dpp_shl1(X.x); Xv[5]=dpp_shl1(X.y); Xv[6]=dpp_shl1(X.z); Xv[7]=dpp_shl1(X.w);
    Yv[4]=dpp_shl1(Y.x); Yv[5]=dpp_shl1(Y.y); Yv[6]=dpp_shl1(Y.z); Yv[7]=dpp_shl1(Y.w);
    Zv[4]=dpp_shl1(Z.x); Zv[5]=dpp_shl1(Z.y); Zv[6]=dpp_shl1(Z.z); Zv[7]=dpp_shl1(Z.w);
    Xv[8]=dpp_shl2(X.x); Xv[9]=dpp_shl2(X.y); Xv[10]=dpp_shl2(X.z); Xv[11]=dpp_shl2(X.w);
    Yv[8]=dpp_shl2(Y.x); Yv[9]=dpp_shl2(Y.y); Yv[10]=dpp_shl2(Y.z); Yv[11]=dpp_shl2(Y.w);
    Zv[8]=dpp_shl2(Z.x); Zv[9]=dpp_shl2(Z.y); Zv[10]=dpp_shl2(Z.z); Zv[11]=dpp_shl2(Z.w);

    float Gv[12], Iv[12], C0[12], C1[12];
    #pragma unroll
    for (int j = 0; j < 12; ++j) {
      Gv[j] = __uint_as_float(Xv[j] & 0xFFFF0000u);
      Iv[j] = __uint_as_float(Xv[j] << 16);
      C0[j] = __uint_as_float(Yv[j] & 0xFFFF0000u);
      C1[j] = __uint_as_float(Yv[j] << 16);
    }

    #pragma unroll
    for (int k = 0; k < 4; ++k) {
      #pragma unroll
      for (int j = k; j < k + 9; ++j) {
        const int xi = j - k;                      // compile-time
        float tden = fmaf(Gv[j], fdr[xi], 1.0f);   // 1 + e^{-8r} e^{8d}
        float w = __builtin_amdgcn_rcpf(tden) * Iv[j];
        wsum[k] += w;
        ac0[k] = fmaf(w, C0[j], ac0[k]);
        ac1[k] = fmaf(w, C1[j], ac1[k]);
        ac2[k] = fmaf(w, __uint_as_float(Zv[j]), ac2[k]);
      }
    }
  }

  const int ox = bx + 4 * tx;
  if (4 * tx < TW && ox + 3 < WW + 1) {
    const int oy = by + ty;
    float rw[4];
    #pragma unroll
    for (int k = 0; k < 4; ++k) rw[k] = __builtin_amdgcn_rcpf(wsum[k]);
    float* op0 = out + ((b * 3 + 0) * HH + oy) * WW + ox;
    float* op1 = out + ((b * 3 + 1) * HH + oy) * WW + ox;
    float* op2 = out + ((b * 3 + 2) * HH + oy) * WW + ox;
    float4 v0, v1, v2;
    v0.x = ac0[0] * rw[0]; v0.y = ac0[1] * rw[1]; v0.z = ac0[2] * rw[2]; v0.w = ac0[3] * rw[3];
    v1.x = ac1[0] * rw[0]; v1.y = ac1[1] * rw[1]; v1.z = ac1[2] * rw[2]; v1.w = ac1[3] * rw[3];
    v2.x = ac2[0] * rw[0]; v2.y = ac2[1] * rw[1]; v2.z = ac2[2] * rw[2]; v2.w = ac2[3] * rw[3];
    *(float4*)op0 = v0;
    *(float4*)op1 = v1;
    *(float4*)op2 = v2;
  }
}

extern "C" void kernel_launch(void* const* d_in, const int* in_sizes, int n_in,
                              void* d_out, int out_size, void* d_ws, size_t ws_size,
                              hipStream_t stream) {
  const float* img = (const float*)d_in[0];   // (2,3,512,512) f32
  const float* def = (const float*)d_in[1];   // (2,1,512,512) f32
  float* out = (float*)d_out;                 // (2,3,512,512) f32

  dim3 grid((WW + TW - 1) / TW, HH / TH, NB);  // 10 x 32 x 2 = 640 blocks
  dim3 block(256);
  hipLaunchKernelGGL(bokeh_gather, grid, block, 0, stream, img, def, out);
}

// Round 10
// 19.360 us; speedup vs baseline: 10.6487x; 1.2418x over previous
//
#include <hip/hip_runtime.h>
#include <cmath>

// Bokeh render, gather form:
// out[b,c,y,x] = sum_{dy,dx in [-4,4]} w * img[b,c,y-dy,x-dx] / sum w
// w = sigmoid(8*(r_src - dist)) / max(pi*r_src^2,1);  r = |defocus| in [0,4).
// Window mask dropped (outside-window w <= sigma(-8): output shift <2e-5).
// OOB sources exact via Iv=0.
//
// R10: OCCUPANCY, done right this time. Evidence: LDS-instr count varied
// 5x (R5:15, R7:9, R9:3 b128/row) with dur ~flat -> not LDS-throughput.
// Measured OccupancyPercent 16-25% (2 waves/SIMD); issue-slot model says
// ~8-10us but measured 20.6 -> latency under-hiding. R3's "occupancy test"
// was void: its dy-split kept grid at 256 blocks = 1 blk/CU = 8 waves/CU.
// Fix: tile 64x16, 512 thr = 2 groups x (16 lanes x 16 rows); group 0 does
// dy 0..4, group 1 dy 5..8; partials combined via LDS. Grid 8x32x2 = 512
// blocks = 2 blk/CU -> 16 waves/CU = 4 waves/SIMD (2x R7), zero tail,
// zero lane waste. Everything else identical to R7 (bf16 3-array packing,
// unroll-1 row loop, sFd LDS broadcasts).

#define HH 512
#define WW 512
#define NB 2
#define TW 64                     // tile width (16 quads, zero waste)
#define TH 16                     // tile height
#define HALO 4
#define SROWS (TH + 2 * HALO)     // 24
#define LW 72                     // 4 + 64 + 4 = exactly 72 dwords/row

__device__ __forceinline__ unsigned rtne_hi(float v) {
  // bf16 round-to-nearest-even, result in HIGH 16 bits (low 16 zero).
  unsigned u = __float_as_uint(v);
  u = u + 0x7FFFu + ((u >> 16) & 1u);
  return u & 0xFFFF0000u;
}

__global__ __launch_bounds__(512, 4) void bokeh_gather(
    const float* __restrict__ img,
    const float* __restrict__ def,
    float* __restrict__ out)
{
  __shared__ __align__(16) unsigned sX[SROWS][LW];  // G(hi) | Iv(lo)   bf16
  __shared__ __align__(16) unsigned sY[SROWS][LW];  // c0(hi) | c1(lo)  bf16
  __shared__ __align__(16) unsigned sZ[SROWS][LW];  // c2 truncated f32
  __shared__ float sFd[9][12];                      // exp(8*dist(dy,dx))
  __shared__ __align__(16) float pbuf[256][20];     // group-1 partials

  const int tid = threadIdx.x;
  const int s   = tid >> 8;      // dy-group: 0 -> dy 0..4, 1 -> dy 5..8
  const int t   = tid & 255;
  const int tx  = t & 15;        // 16 lanes * 4 px = 64 cols
  const int ty  = t >> 4;        // 16 rows
  const int bx = blockIdx.x * TW;
  const int by = blockIdx.y * TH;
  const int b  = blockIdx.z;

  if (tid < 81) {
    int dyi = tid / 9, dxi = tid - dyi * 9;
    int dyo = dyi - 4, dxo = dxi - 4;
    float d2 = (float)(dyo * dyo + dxo * dxo);
    sFd[dyi][dxi] = __expf(8.0f * sqrtf(d2));
  }

  const float* dpt = def + b * (HH * WW);
  const float* ipt = img + b * (3 * HH * WW);

  // Stage halo'd tile: 24 rows x 72 cols = 1728 px / 512 thr = 4 iters.
  // OOB -> zeros => w = 0 exactly.
  for (int idx = tid; idx < SROWS * LW; idx += 512) {
    int ly = idx / LW;
    int lx = idx - ly * LW;
    int sy = by - HALO + ly;
    int sx = bx - HALO + lx;
    unsigned X = 0u, Y = 0u, Z = 0u;
    if ((unsigned)sy < (unsigned)HH && (unsigned)sx < (unsigned)WW) {
      int o = sy * WW + sx;
      float r = fabsf(dpt[o]);
      float G  = __expf(-8.0f * r);
      float iv = __builtin_amdgcn_rcpf(fmaxf(3.14159265358979f * r * r, 1.0f));
      X = rtne_hi(G) | (rtne_hi(iv) >> 16);
      Y = rtne_hi(ipt[o]) | (rtne_hi(ipt[o + HH * WW]) >> 16);
      Z = __float_as_uint(ipt[o + 2 * HH * WW]) & 0xFFFF0000u;
    }
    sX[ly][lx] = X;
    sY[ly][lx] = Y;
    sZ[ly][lx] = Z;
  }
  __syncthreads();

  float wsum[4] = {0.f, 0.f, 0.f, 0.f};
  float ac0[4]  = {0.f, 0.f, 0.f, 0.f};
  float ac1[4]  = {0.f, 0.f, 0.f, 0.f};
  float ac2[4]  = {0.f, 0.f, 0.f, 0.f};

  const int col0 = 4 * tx;       // window start col (16B aligned)
  const int dy0 = s ? 5 : 0;
  const int dy1 = s ? 9 : 5;

  #pragma unroll 1
  for (int dy = dy0; dy < dy1; ++dy) {
    const int sr = ty + dy;
    float fdr[9];
    #pragma unroll
    for (int x = 0; x < 9; ++x) fdr[x] = sFd[dy][x];

    unsigned Xv[12], Yv[12], Zv[12];
    #pragma unroll
    for (int q = 0; q < 3; ++q) {
      *(uint4*)&Xv[4 * q] = *(const uint4*)(&sX[sr][col0] + 4 * q);
      *(uint4*)&Yv[4 * q] = *(const uint4*)(&sY[sr][col0] + 4 * q);
      *(uint4*)&Zv[4 * q] = *(const uint4*)(&sZ[sr][col0] + 4 * q);
    }
    float Gv[12], Iv[12], C0[12], C1[12];
    #pragma unroll
    for (int j = 0; j < 12; ++j) {
      Gv[j] = __uint_as_float(Xv[j] & 0xFFFF0000u);
      Iv[j] = __uint_as_float(Xv[j] << 16);
      C0[j] = __uint_as_float(Yv[j] & 0xFFFF0000u);
      C1[j] = __uint_as_float(Yv[j] << 16);
    }

    #pragma unroll
    for (int k = 0; k < 4; ++k) {
      #pragma unroll
      for (int j = k; j < k + 9; ++j) {
        const int xi = j - k;                      // compile-time
        float tden = fmaf(Gv[j], fdr[xi], 1.0f);   // 1 + e^{-8r} e^{8d}
        float w = __builtin_amdgcn_rcpf(tden) * Iv[j];
        wsum[k] += w;
        ac0[k] = fmaf(w, C0[j], ac0[k]);
        ac1[k] = fmaf(w, C1[j], ac1[k]);
        ac2[k] = fmaf(w, __uint_as_float(Zv[j]), ac2[k]);
      }
    }
  }

  // Combine dy-halves: group 1 publishes, group 0 reduces + stores.
  if (s == 1) {
    float4 v0 = {wsum[0], wsum[1], wsum[2], wsum[3]};
    float4 v1 = {ac0[0], ac0[1], ac0[2], ac0[3]};
    float4 v2 = {ac1[0], ac1[1], ac1[2], ac1[3]};
    float4 v3 = {ac2[0], ac2[1], ac2[2], ac2[3]};
    *(float4*)&pbuf[t][0]  = v0;
    *(float4*)&pbuf[t][4]  = v1;
    *(float4*)&pbuf[t][8]  = v2;
    *(float4*)&pbuf[t][12] = v3;
  }
  __syncthreads();
  if (s == 0) {
    float4 v0 = *(const float4*)&pbuf[t][0];
    float4 v1 = *(const float4*)&pbuf[t][4];
    float4 v2 = *(const float4*)&pbuf[t][8];
    float4 v3 = *(const float4*)&pbuf[t][12];
    wsum[0] += v0.x; wsum[1] += v0.y; wsum[2] += v0.z; wsum[3] += v0.w;
    ac0[0] += v1.x; ac0[1] += v1.y; ac0[2] += v1.z; ac0[3] += v1.w;
    ac1[0] += v2.x; ac1[1] += v2.y; ac1[2] += v2.z; ac1[3] += v2.w;
    ac2[0] += v3.x; ac2[1] += v3.y; ac2[2] += v3.z; ac2[3] += v3.w;

    const int oy = by + ty;
    const int ox = bx + col0;
    float rw[4];
    #pragma unroll
    for (int k = 0; k < 4; ++k) rw[k] = __builtin_amdgcn_rcpf(wsum[k]);

    float* op0 = out + ((b * 3 + 0) * HH + oy) * WW + ox;
    float* op1 = out + ((b * 3 + 1) * HH + oy) * WW + ox;
    float* op2 = out + ((b * 3 + 2) * HH + oy) * WW + ox;
    float4 o0, o1, o2;
    o0.x = ac0[0] * rw[0]; o0.y = ac0[1] * rw[1]; o0.z = ac0[2] * rw[2]; o0.w = ac0[3] * rw[3];
    o1.x = ac1[0] * rw[0]; o1.y = ac1[1] * rw[1]; o1.z = ac1[2] * rw[2]; o1.w = ac1[3] * rw[3];
    o2.x = ac2[0] * rw[0]; o2.y = ac2[1] * rw[1]; o2.z = ac2[2] * rw[2]; o2.w = ac2[3] * rw[3];
    *(float4*)op0 = o0;
    *(float4*)op1 = o1;
    *(float4*)op2 = o2;
  }
}

extern "C" void kernel_launch(void* const* d_in, const int* in_sizes, int n_in,
                              void* d_out, int out_size, void* d_ws, size_t ws_size,
                              hipStream_t stream) {
  const float* img = (const float*)d_in[0];   // (2,3,512,512) f32
  const float* def = (const float*)d_in[1];   // (2,1,512,512) f32
  float* out = (float*)d_out;                 // (2,3,512,512) f32

  dim3 grid(WW / TW, HH / TH, NB);            // 8 x 32 x 2 = 512 blocks = 2/CU
  dim3 block(512);
  hipLaunchKernelGGL(bokeh_gather, grid, block, 0, stream, img, def, out);
}